// Round 1
// baseline (382.034 us; speedup 1.0000x reference)
//
#include <hip/hip_runtime.h>
#include <stdint.h>

typedef short short8 __attribute__((ext_vector_type(8)));
typedef short short4v __attribute__((ext_vector_type(4)));
typedef float f32x4 __attribute__((ext_vector_type(4)));
typedef float float4v __attribute__((ext_vector_type(4)));

__device__ inline float bf2f(short s) {
    union { unsigned u; float f; } c;
    c.u = ((unsigned)(unsigned short)s) << 16;
    return c.f;
}
__device__ inline short f2bf(float f) {
    union { float f; unsigned u; } c;
    c.f = f;
    unsigned u = c.u;
    unsigned r = (u + 0x7fffu + ((u >> 16) & 1u)) >> 16;
    return (short)r;
}

// ---------------- weight fp32 -> bf16 convert ----------------
__global__ __launch_bounds__(256) void conv_w(const float* __restrict__ src, short* __restrict__ dst) {
    int i = (blockIdx.x * 256 + threadIdx.x) * 4;
    float4v v = *reinterpret_cast<const float4v*>(src + i);
    short4v o;
    o[0] = f2bf(v[0]); o[1] = f2bf(v[1]); o[2] = f2bf(v[2]); o[3] = f2bf(v[3]);
    *reinterpret_cast<short4v*>(dst + i) = o;
}

// ---------------- GroupNorm stats: one block per (b,g) ----------------
__global__ __launch_bounds__(256) void gn_stats(const float* __restrict__ x, float* __restrict__ stats) {
    int bg = blockIdx.x;  // b*32 + g
    const float* p = x + (size_t)bg * (16 * 4096);
    float s = 0.f, ss = 0.f;
    for (int i = threadIdx.x * 4; i < 65536; i += 1024) {
        float4v q = *reinterpret_cast<const float4v*>(p + i);
        s  += q[0] + q[1] + q[2] + q[3];
        ss += q[0]*q[0] + q[1]*q[1] + q[2]*q[2] + q[3]*q[3];
    }
    #pragma unroll
    for (int off = 32; off >= 1; off >>= 1) {
        s  += __shfl_xor(s, off);
        ss += __shfl_xor(ss, off);
    }
    __shared__ float rs[8];
    int w = threadIdx.x >> 6, lane = threadIdx.x & 63;
    if (lane == 0) { rs[w] = s; rs[4 + w] = ss; }
    __syncthreads();
    if (threadIdx.x == 0) {
        float S1 = rs[0] + rs[1] + rs[2] + rs[3];
        float S2 = rs[4] + rs[5] + rs[6] + rs[7];
        float mean = S1 * (1.f / 65536.f);
        float var  = S2 * (1.f / 65536.f) - mean * mean;
        stats[bg * 2]     = mean;
        stats[bg * 2 + 1] = rsqrtf(var + 1e-6f);
    }
}

// ---------------- GN apply + transpose: x[b][c][n] -> hT[b][n][c] (bf16) ----------------
__global__ __launch_bounds__(256) void gn_apply_t(const float* __restrict__ x, const float* __restrict__ stats,
                                                  const float* __restrict__ scale, const float* __restrict__ bias,
                                                  short* __restrict__ hT) {
    __shared__ float t[64][65];
    int n0 = blockIdx.x * 64, c0 = blockIdx.y * 64, b = blockIdx.z;
    const float* xb = x + (size_t)b * 512 * 4096;
    int col = threadIdx.x & 63, rb = threadIdx.x >> 6;  // col: n_local on read, c_local on write
    #pragma unroll
    for (int r = 0; r < 16; ++r) {
        int cl = rb + r * 4;
        int c = c0 + cl;
        int g = c >> 4;
        float mean = stats[(b * 32 + g) * 2];
        float rstd = stats[(b * 32 + g) * 2 + 1];
        float v = xb[(size_t)c * 4096 + n0 + col];
        t[col][cl] = (v - mean) * rstd * scale[c] + bias[c];
    }
    __syncthreads();
    short* hb = hT + (size_t)b * 4096 * 512;
    #pragma unroll
    for (int r = 0; r < 16; ++r) {
        int nl = rb + r * 4;
        hb[(size_t)(n0 + nl) * 512 + c0 + col] = f2bf(t[nl][col]);
    }
}

// ---------------- NT GEMM: C[M][N] = A[M][K] * B[N][K]^T  (bf16 in, fp32 acc) ----------------
// bias_mode: 0 none, 1 bias[row], 2 bias[col].  C = (acc + bias) * alpha  (+ res if fp32 out)
#define BM 128
#define BN 128
#define BK 64

__global__ __launch_bounds__(256) void gemm_nt(
    const short* __restrict__ A, long sAb,
    const short* __restrict__ B, long sBb,    
    void* __restrict__ Cv, long sCb,
    int M, int N, int K,
    const float* __restrict__ bias, int bias_mode,
    float alpha,
    const float* __restrict__ res, long sResb,
    int c_fp32)
{
    __shared__ __align__(16) char lds[2 * BM * 128];
    char* ldsA = lds;
    char* ldsB = lds + BM * 128;

    const int tid = threadIdx.x;
    const int bm = blockIdx.x * BM;
    const int bn = blockIdx.y * BN;
    const int bz = blockIdx.z;

    const short* Ab = A + (size_t)bz * sAb;
    const short* Bb = B + (size_t)bz * sBb;

    const int w = tid >> 6;
    const int lane = tid & 63;
    const int wr = (w >> 1) * 64;
    const int wc = (w & 1) * 64;

    const int lrow = tid >> 3;  // 0..31
    const int lkb  = tid & 7;   // 16B block within a 128B row

    f32x4 acc[4][4] = {};

    for (int kt = 0; kt < K; kt += BK) {
        short8 ra[4], rb[4];
        #pragma unroll
        for (int i = 0; i < 4; ++i) {
            int r = i * 32 + lrow;
            ra[i] = *reinterpret_cast<const short8*>(Ab + (size_t)(bm + r) * K + kt + lkb * 8);
            rb[i] = *reinterpret_cast<const short8*>(Bb + (size_t)(bn + r) * K + kt + lkb * 8);
        }
        __syncthreads();
        #pragma unroll
        for (int i = 0; i < 4; ++i) {
            int r = i * 32 + lrow;
            int off = r * 128 + ((lkb * 16) ^ ((r & 7) << 4));
            *reinterpret_cast<short8*>(ldsA + off) = ra[i];
            *reinterpret_cast<short8*>(ldsB + off) = rb[i];
        }
        __syncthreads();
        #pragma unroll
        for (int ks = 0; ks < 2; ++ks) {
            const int kb = ks * 64 + (lane >> 4) * 16;
            short8 af[4], bfr[4];
            #pragma unroll
            for (int m = 0; m < 4; ++m) {
                int r = wr + m * 16 + (lane & 15);
                af[m] = *reinterpret_cast<const short8*>(ldsA + r * 128 + (kb ^ ((r & 7) << 4)));
            }
            #pragma unroll
            for (int n = 0; n < 4; ++n) {
                int r = wc + n * 16 + (lane & 15);
                bfr[n] = *reinterpret_cast<const short8*>(ldsB + r * 128 + (kb ^ ((r & 7) << 4)));
            }
            #pragma unroll
            for (int m = 0; m < 4; ++m)
                #pragma unroll
                for (int n = 0; n < 4; ++n)
                    acc[m][n] = __builtin_amdgcn_mfma_f32_16x16x32_bf16(af[m], bfr[n], acc[m][n], 0, 0, 0);
        }
    }

    const int row0 = (lane >> 4) * 4;
    const int col0 = lane & 15;
    short* Cb16 = (short*)Cv + (size_t)bz * sCb;
    float* Cf32 = (float*)Cv + (size_t)bz * sCb;
    const float* resb = res ? res + (size_t)bz * sResb : nullptr;

    #pragma unroll
    for (int m = 0; m < 4; ++m) {
        #pragma unroll
        for (int r = 0; r < 4; ++r) {
            int row = bm + wr + m * 16 + row0 + r;
            float bvr = (bias_mode == 1) ? bias[row] : 0.0f;
            #pragma unroll
            for (int n = 0; n < 4; ++n) {
                int col = bn + wc + n * 16 + col0;
                float v = acc[m][n][r];
                if (bias_mode == 1) v += bvr;
                else if (bias_mode == 2) v += bias[col];
                v *= alpha;
                size_t idx = (size_t)row * N + col;
                if (c_fp32) {
                    if (resb) v += resb[idx];
                    Cf32[idx] = v;
                } else {
                    Cb16[idx] = f2bf(v);
                }
            }
        }
    }
}

// ---------------- row softmax in-place on bf16 [4096] rows ----------------
__global__ __launch_bounds__(256) void softmax_rows(short* __restrict__ S) {
    const int N = 4096;
    short* p = S + (size_t)blockIdx.x * N + threadIdx.x * 16;
    short8 r0 = *reinterpret_cast<short8*>(p);
    short8 r1 = *reinterpret_cast<short8*>(p + 8);
    float v[16];
    #pragma unroll
    for (int i = 0; i < 8; ++i) { v[i] = bf2f(r0[i]); v[8 + i] = bf2f(r1[i]); }
    float mx = v[0];
    #pragma unroll
    for (int i = 1; i < 16; ++i) mx = fmaxf(mx, v[i]);
    #pragma unroll
    for (int off = 32; off >= 1; off >>= 1) mx = fmaxf(mx, __shfl_xor(mx, off));
    __shared__ float red[8];
    int w = threadIdx.x >> 6, lane = threadIdx.x & 63;
    if (lane == 0) red[w] = mx;
    __syncthreads();
    mx = fmaxf(fmaxf(red[0], red[1]), fmaxf(red[2], red[3]));
    float s = 0.f;
    #pragma unroll
    for (int i = 0; i < 16; ++i) { v[i] = __expf(v[i] - mx); s += v[i]; }
    #pragma unroll
    for (int off = 32; off >= 1; off >>= 1) s += __shfl_xor(s, off);
    if (lane == 0) red[4 + w] = s;
    __syncthreads();
    s = (red[4] + red[5]) + (red[6] + red[7]);
    float inv = 1.0f / s;
    #pragma unroll
    for (int i = 0; i < 8; ++i) { r0[i] = f2bf(v[i] * inv); r1[i] = f2bf(v[8 + i] * inv); }
    *reinterpret_cast<short8*>(p) = r0;
    *reinterpret_cast<short8*>(p + 8) = r1;
}

extern "C" void kernel_launch(void* const* d_in, const int* in_sizes, int n_in,
                              void* d_out, int out_size, void* d_ws, size_t ws_size,
                              hipStream_t stream) {
    (void)in_sizes; (void)n_in; (void)out_size; (void)ws_size;
    const float* x        = (const float*)d_in[0];
    const float* gn_scale = (const float*)d_in[1];
    const float* gn_bias  = (const float*)d_in[2];
    const float* wq = (const float*)d_in[3];
    const float* bq = (const float*)d_in[4];
    const float* wk = (const float*)d_in[5];
    const float* bk = (const float*)d_in[6];
    const float* wv = (const float*)d_in[7];
    const float* bv = (const float*)d_in[8];
    const float* wp = (const float*)d_in[9];
    const float* bp = (const float*)d_in[10];

    char* ws = (char*)d_ws;
    const size_t MB = 1024 * 1024;
    short* hT  = (short*)(ws + 0);        // [2][4096][512] bf16
    short* QT  = (short*)(ws + 8  * MB);  // [2][4096][512]
    short* KT  = (short*)(ws + 16 * MB);  // [2][4096][512]
    short* V   = (short*)(ws + 24 * MB);  // [2][512][4096]
    short* OT  = (short*)(ws + 32 * MB);  // [2][4096][512]
    short* S   = (short*)(ws + 40 * MB);  // [4096][4096] (per-batch reuse)
    short* wB  = (short*)(ws + 72 * MB);  // wq,wk,wv,wp bf16, 512*512 each
    float* stats = (float*)(ws + 74 * MB);

    const long NC = 4096L * 512L;   // 2M elements
    const long CN = 512L * 4096L;

    conv_w<<<256, 256, 0, stream>>>(wq, wB);
    conv_w<<<256, 256, 0, stream>>>(wk, wB + 262144);
    conv_w<<<256, 256, 0, stream>>>(wv, wB + 524288);
    conv_w<<<256, 256, 0, stream>>>(wp, wB + 786432);

    gn_stats<<<64, 256, 0, stream>>>(x, stats);
    gn_apply_t<<<dim3(64, 8, 2), 256, 0, stream>>>(x, stats, gn_scale, gn_bias, hT);

    const float attn_scale = 0.044194173824159216f;  // 512^-0.5

    // QT[b][n][c] = (hT . wq^T + bq) * scale
    gemm_nt<<<dim3(32, 4, 2), 256, 0, stream>>>(hT, NC, wB, 0, QT, NC,
                                                4096, 512, 512, bq, 2, attn_scale, nullptr, 0, 0);
    // KT[b][n][c]
    gemm_nt<<<dim3(32, 4, 2), 256, 0, stream>>>(hT, NC, wB + 262144, 0, KT, NC,
                                                4096, 512, 512, bk, 2, 1.0f, nullptr, 0, 0);
    // V[b][c][n] = wv . h + bv
    gemm_nt<<<dim3(4, 32, 2), 256, 0, stream>>>(wB + 524288, 0, hT, NC, V, CN,
                                                512, 4096, 512, bv, 1, 1.0f, nullptr, 0, 0);

    for (int b = 0; b < 2; ++b) {
        // S[i][j] = sum_c QT[i][c] * KT[j][c]
        gemm_nt<<<dim3(32, 32, 1), 256, 0, stream>>>(QT + (size_t)b * NC, 0, KT + (size_t)b * NC, 0,
                                                     S, 0, 4096, 4096, 512, nullptr, 0, 1.0f, nullptr, 0, 0);
        softmax_rows<<<4096, 256, 0, stream>>>(S);
        // OT[i][c] = sum_j P[i][j] * V[c][j]
        gemm_nt<<<dim3(32, 4, 1), 256, 0, stream>>>(S, 0, V + (size_t)b * CN, 0,
                                                    OT + (size_t)b * NC, 0, 4096, 512, 4096,
                                                    nullptr, 0, 1.0f, nullptr, 0, 0);
    }

    // out[b][c][n] = wp . o + bp + x   (fp32 out)
    gemm_nt<<<dim3(4, 32, 2), 256, 0, stream>>>(wB + 786432, 0, OT, NC, d_out, CN,
                                                512, 4096, 512, bp, 1, 1.0f, x, CN, 1);
}

// Round 2
// 259.136 us; speedup vs baseline: 1.4743x; 1.4743x over previous
//
#include <hip/hip_runtime.h>
#include <stdint.h>

typedef short short8 __attribute__((ext_vector_type(8)));
typedef short short4v __attribute__((ext_vector_type(4)));
typedef float f32x4 __attribute__((ext_vector_type(4)));
typedef float float4v __attribute__((ext_vector_type(4)));

__device__ inline float bf2f(short s) {
    union { unsigned u; float f; } c;
    c.u = ((unsigned)(unsigned short)s) << 16;
    return c.f;
}
__device__ inline short f2bf(float f) {
    union { float f; unsigned u; } c;
    c.f = f;
    unsigned u = c.u;
    unsigned r = (u + 0x7fffu + ((u >> 16) & 1u)) >> 16;
    return (short)r;
}

typedef const __attribute__((address_space(1))) char GChar;
typedef __attribute__((address_space(3))) char LChar;
__device__ __forceinline__ void gload_lds16(const void* g, void* l) {
    __builtin_amdgcn_global_load_lds((GChar*)g, (LChar*)l, 16, 0, 0);
}

// ---------------- weight fp32 -> bf16 convert (with scale fold) ----------------
__global__ __launch_bounds__(256) void conv_w(const float* __restrict__ src, short* __restrict__ dst, float scale) {
    int i = (blockIdx.x * 256 + threadIdx.x) * 4;
    float4v v = *reinterpret_cast<const float4v*>(src + i);
    short4v o;
    o[0] = f2bf(v[0] * scale); o[1] = f2bf(v[1] * scale);
    o[2] = f2bf(v[2] * scale); o[3] = f2bf(v[3] * scale);
    *reinterpret_cast<short4v*>(dst + i) = o;
}

// bqk[0:512] = bq*s ; bqk[512:1024] = bk
__global__ __launch_bounds__(256) void prep_bias(const float* __restrict__ bq, const float* __restrict__ bk,
                                                 float* __restrict__ bqk, float s) {
    int i = blockIdx.x * 256 + threadIdx.x;
    bqk[i] = (i < 512) ? bq[i] * s : bk[i - 512];
}

// ---------------- GroupNorm stats: one block per (b,g) ----------------
__global__ __launch_bounds__(256) void gn_stats(const float* __restrict__ x, float* __restrict__ stats) {
    int bg = blockIdx.x;
    const float* p = x + (size_t)bg * (16 * 4096);
    float s = 0.f, ss = 0.f;
    for (int i = threadIdx.x * 4; i < 65536; i += 1024) {
        float4v q = *reinterpret_cast<const float4v*>(p + i);
        s  += q[0] + q[1] + q[2] + q[3];
        ss += q[0]*q[0] + q[1]*q[1] + q[2]*q[2] + q[3]*q[3];
    }
    #pragma unroll
    for (int off = 32; off >= 1; off >>= 1) {
        s  += __shfl_xor(s, off);
        ss += __shfl_xor(ss, off);
    }
    __shared__ float rs[8];
    int w = threadIdx.x >> 6, lane = threadIdx.x & 63;
    if (lane == 0) { rs[w] = s; rs[4 + w] = ss; }
    __syncthreads();
    if (threadIdx.x == 0) {
        float S1 = rs[0] + rs[1] + rs[2] + rs[3];
        float S2 = rs[4] + rs[5] + rs[6] + rs[7];
        float mean = S1 * (1.f / 65536.f);
        float var  = S2 * (1.f / 65536.f) - mean * mean;
        stats[bg * 2]     = mean;
        stats[bg * 2 + 1] = rsqrtf(var + 1e-6f);
    }
}

// ---------------- GN apply + transpose: x[b][c][n] -> hT[b][n][c] (bf16) ----------------
__global__ __launch_bounds__(256) void gn_apply_t(const float* __restrict__ x, const float* __restrict__ stats,
                                                  const float* __restrict__ scale, const float* __restrict__ bias,
                                                  short* __restrict__ hT) {
    __shared__ float t[64][65];
    int n0 = blockIdx.x * 64, c0 = blockIdx.y * 64, b = blockIdx.z;
    const float* xb = x + (size_t)b * 512 * 4096;
    int col = threadIdx.x & 63, rb = threadIdx.x >> 6;
    #pragma unroll
    for (int r = 0; r < 16; ++r) {
        int cl = rb + r * 4;
        int c = c0 + cl;
        int g = c >> 4;
        float mean = stats[(b * 32 + g) * 2];
        float rstd = stats[(b * 32 + g) * 2 + 1];
        float v = xb[(size_t)c * 4096 + n0 + col];
        t[col][cl] = (v - mean) * rstd * scale[c] + bias[c];
    }
    __syncthreads();
    short* hb = hT + (size_t)b * 4096 * 512;
    #pragma unroll
    for (int r = 0; r < 16; ++r) {
        int nl = rb + r * 4;
        hb[(size_t)(n0 + nl) * 512 + c0 + col] = f2bf(t[nl][col]);
    }
}

// ---------------- NT GEMM, 2-phase pipelined, global_load_lds staging ----------------
// C[M][N] = A[M][K] * B[N][K]^T ; bf16 in, fp32 acc.
// BM=128 fixed, BN templated. BK=64. LDS double-buffered, XOR-swizzled via
// inverse-swizzled global source (linear LDS dest for global_load_lds).
// bias_mode: 0 none, 1 bias[row], 2 bias[col].
template<int BNT>
__global__ __launch_bounds__(256) void gemm_nt2(
    const short* __restrict__ A, long sAb, int lda,
    const short* __restrict__ B, long sBb, int ldb,
    void* __restrict__ Cv, long sCb, int ldc,
    int K,
    const float* __restrict__ bias, int bias_mode,
    const float* __restrict__ res, long sResb,
    int c_fp32)
{
    constexpr int BMT = 128;
    constexpr int NF  = BNT / 32;            // B frags per wave
    constexpr int BUF = (BMT + BNT) * 128;   // bytes per buffer (rows x 128B)
    __shared__ __align__(16) char lds[2 * BUF];

    const int tid = threadIdx.x;
    const int bm = blockIdx.x * BMT;
    const int bn = blockIdx.y * BNT;
    const int bz = blockIdx.z;

    const short* Ab = A + (size_t)bz * sAb;
    const short* Bb = B + (size_t)bz * sBb;

    const int w = tid >> 6;
    const int lane = tid & 63;
    const int wr = (w >> 1) * 64;
    const int wc = (w & 1) * (BNT / 2);

    f32x4 acc[4][NF] = {};

    const int nk = K >> 6;

    // ---- stage tile kt into buffer buf (linear LDS dest, inverse-swizzled source) ----
    auto stage = [&](int buf, int kt) {
        char* la = lds + buf * BUF;
        char* lb = la + BMT * 128;
        #pragma unroll
        for (int i = 0; i < (BMT * 8) / 256; ++i) {
            int ch = i * 256 + tid;
            int r = ch >> 3, c = ch & 7;
            const short* g = Ab + (size_t)(bm + r) * lda + kt + ((c ^ (r & 7)) << 3);
            gload_lds16(g, la + ch * 16);
        }
        #pragma unroll
        for (int i = 0; i < (BNT * 8) / 256; ++i) {
            int ch = i * 256 + tid;
            int r = ch >> 3, c = ch & 7;
            const short* g = Bb + (size_t)(bn + r) * ldb + kt + ((c ^ (r & 7)) << 3);
            gload_lds16(g, lb + ch * 16);
        }
    };

    stage(0, 0);
    __syncthreads();

    int cur = 0;
    for (int t = 0; t < nk; ++t) {
        if (t + 1 < nk) stage(cur ^ 1, (t + 1) << 6);
        const char* la = lds + cur * BUF;
        const char* lb = la + BMT * 128;
        #pragma unroll
        for (int ks = 0; ks < 2; ++ks) {
            const int kb = ks * 64 + (lane >> 4) * 16;
            short8 af[4], bfv[NF];
            #pragma unroll
            for (int m = 0; m < 4; ++m) {
                int r = wr + m * 16 + (lane & 15);
                af[m] = *reinterpret_cast<const short8*>(la + r * 128 + (kb ^ ((r & 7) << 4)));
            }
            #pragma unroll
            for (int n = 0; n < NF; ++n) {
                int r = wc + n * 16 + (lane & 15);
                bfv[n] = *reinterpret_cast<const short8*>(lb + r * 128 + (kb ^ ((r & 7) << 4)));
            }
            #pragma unroll
            for (int m = 0; m < 4; ++m)
                #pragma unroll
                for (int n = 0; n < NF; ++n)
                    acc[m][n] = __builtin_amdgcn_mfma_f32_16x16x32_bf16(af[m], bfv[n], acc[m][n], 0, 0, 0);
        }
        if (t + 1 < nk) __syncthreads();
        cur ^= 1;
    }

    const int row0 = (lane >> 4) * 4;
    const int col0 = lane & 15;
    short* Cb16 = (short*)Cv + (size_t)bz * sCb;
    float* Cf32 = (float*)Cv + (size_t)bz * sCb;
    const float* resb = res ? res + (size_t)bz * sResb : nullptr;

    #pragma unroll
    for (int m = 0; m < 4; ++m) {
        #pragma unroll
        for (int r = 0; r < 4; ++r) {
            int row = bm + wr + m * 16 + row0 + r;
            float bvr = (bias_mode == 1) ? bias[row] : 0.0f;
            #pragma unroll
            for (int n = 0; n < NF; ++n) {
                int col = bn + wc + n * 16 + col0;
                float v = acc[m][n][r];
                if (bias_mode == 1) v += bvr;
                else if (bias_mode == 2) v += bias[col];
                size_t idx = (size_t)row * ldc + col;
                if (c_fp32) {
                    if (resb) v += resb[idx];
                    Cf32[idx] = v;
                } else {
                    Cb16[idx] = f2bf(v);
                }
            }
        }
    }
}

// ---------------- row softmax in-place on bf16 [4096] rows ----------------
__global__ __launch_bounds__(256) void softmax_rows(short* __restrict__ S) {
    const int N = 4096;
    short* p = S + (size_t)blockIdx.x * N + threadIdx.x * 16;
    short8 r0 = *reinterpret_cast<short8*>(p);
    short8 r1 = *reinterpret_cast<short8*>(p + 8);
    float v[16];
    #pragma unroll
    for (int i = 0; i < 8; ++i) { v[i] = bf2f(r0[i]); v[8 + i] = bf2f(r1[i]); }
    float mx = v[0];
    #pragma unroll
    for (int i = 1; i < 16; ++i) mx = fmaxf(mx, v[i]);
    #pragma unroll
    for (int off = 32; off >= 1; off >>= 1) mx = fmaxf(mx, __shfl_xor(mx, off));
    __shared__ float red[8];
    int w = threadIdx.x >> 6, lane = threadIdx.x & 63;
    if (lane == 0) red[w] = mx;
    __syncthreads();
    mx = fmaxf(fmaxf(red[0], red[1]), fmaxf(red[2], red[3]));
    float s = 0.f;
    #pragma unroll
    for (int i = 0; i < 16; ++i) { v[i] = __expf(v[i] - mx); s += v[i]; }
    #pragma unroll
    for (int off = 32; off >= 1; off >>= 1) s += __shfl_xor(s, off);
    if (lane == 0) red[4 + w] = s;
    __syncthreads();
    s = (red[4] + red[5]) + (red[6] + red[7]);
    float inv = 1.0f / s;
    #pragma unroll
    for (int i = 0; i < 8; ++i) { r0[i] = f2bf(v[i] * inv); r1[i] = f2bf(v[8 + i] * inv); }
    *reinterpret_cast<short8*>(p) = r0;
    *reinterpret_cast<short8*>(p + 8) = r1;
}

// ---------------- split-K reduce: OT_bf16 = sum of 4 fp32 partials ----------------
__global__ __launch_bounds__(256) void reduce4(const float* __restrict__ p, short* __restrict__ o) {
    const long NN = 4096L * 512L;
    int i = (blockIdx.x * 256 + threadIdx.x) * 4;
    float4v a = *reinterpret_cast<const float4v*>(p + i);
    float4v b = *reinterpret_cast<const float4v*>(p + NN + i);
    float4v c = *reinterpret_cast<const float4v*>(p + 2 * NN + i);
    float4v d = *reinterpret_cast<const float4v*>(p + 3 * NN + i);
    short4v o4;
    o4[0] = f2bf(a[0] + b[0] + c[0] + d[0]);
    o4[1] = f2bf(a[1] + b[1] + c[1] + d[1]);
    o4[2] = f2bf(a[2] + b[2] + c[2] + d[2]);
    o4[3] = f2bf(a[3] + b[3] + c[3] + d[3]);
    *reinterpret_cast<short4v*>(o + i) = o4;
}

extern "C" void kernel_launch(void* const* d_in, const int* in_sizes, int n_in,
                              void* d_out, int out_size, void* d_ws, size_t ws_size,
                              hipStream_t stream) {
    (void)in_sizes; (void)n_in; (void)out_size; (void)ws_size;
    const float* x        = (const float*)d_in[0];
    const float* gn_scale = (const float*)d_in[1];
    const float* gn_bias  = (const float*)d_in[2];
    const float* wq = (const float*)d_in[3];
    const float* bq = (const float*)d_in[4];
    const float* wk = (const float*)d_in[5];
    const float* bk = (const float*)d_in[6];
    const float* wv = (const float*)d_in[7];
    const float* bv = (const float*)d_in[8];
    const float* wp = (const float*)d_in[9];
    const float* bp = (const float*)d_in[10];

    char* ws = (char*)d_ws;
    const size_t MB = 1024 * 1024;
    short* hT   = (short*)(ws + 0);        // [2][4096][512] bf16    (8MB)
    short* QKT  = (short*)(ws + 8  * MB);  // [2][4096][1024] bf16  (16MB)
    short* V    = (short*)(ws + 24 * MB);  // [2][512][4096] bf16    (8MB)
    short* OT   = (short*)(ws + 32 * MB);  // [2][4096][512] bf16    (8MB)
    short* S    = (short*)(ws + 40 * MB);  // [4096][4096] bf16     (32MB, per-batch reuse)
    short* wB   = (short*)(ws + 72 * MB);  // wq,wk,wv,wp bf16       (2MB)
    float* stats= (float*)(ws + 74 * MB);  // 128 f
    float* bqk  = (float*)(ws + 74 * MB + 4096);  // 1024 f
    float* part = (float*)(ws + 75 * MB);  // [4][4096][512] fp32   (32MB, per-batch reuse)

    const long NC   = 4096L * 512L;
    const long CN   = 512L * 4096L;
    const long QKNC = 4096L * 1024L;
    const float attn_scale = 0.044194173824159216f;  // 512^-0.5

    conv_w<<<256, 256, 0, stream>>>(wq, wB,          attn_scale);
    conv_w<<<256, 256, 0, stream>>>(wk, wB + 262144, 1.0f);
    conv_w<<<256, 256, 0, stream>>>(wv, wB + 524288, 1.0f);
    conv_w<<<256, 256, 0, stream>>>(wp, wB + 786432, 1.0f);
    prep_bias<<<4, 256, 0, stream>>>(bq, bk, bqk, attn_scale);

    gn_stats<<<64, 256, 0, stream>>>(x, stats);
    gn_apply_t<<<dim3(64, 8, 2), 256, 0, stream>>>(x, stats, gn_scale, gn_bias, hT);

    // QK projection (merged): QKT[b][n][0:512]=Q*s, [512:1024]=K
    gemm_nt2<128><<<dim3(32, 8, 2), 256, 0, stream>>>(
        hT, NC, 512, wB, 0, 512, QKT, QKNC, 1024, 512, bqk, 2, nullptr, 0, 0);
    // V[b][c][n]
    gemm_nt2<64><<<dim3(4, 64, 2), 256, 0, stream>>>(
        wB + 524288, 0, 512, hT, NC, 512, V, CN, 4096, 512, bv, 1, nullptr, 0, 0);

    for (int b = 0; b < 2; ++b) {
        const short* Qb = QKT + (size_t)b * QKNC;
        // S[i][j] = sum_c Q[i][c] K[j][c]  (scale pre-folded)
        gemm_nt2<128><<<dim3(32, 32, 1), 256, 0, stream>>>(
            Qb, 0, 1024, Qb + 512, 0, 1024, S, 0, 4096, 512, nullptr, 0, nullptr, 0, 0);
        softmax_rows<<<4096, 256, 0, stream>>>(S);
        // PV split-K=4: part[z][i][c] = sum_{j in z-slice} P[i][j] V[c][j]
        gemm_nt2<64><<<dim3(32, 8, 4), 256, 0, stream>>>(
            S, 1024, 4096, V + (size_t)b * CN, 1024, 4096, part, 4096L * 512L, 512, 1024,
            nullptr, 0, nullptr, 0, 1);
        reduce4<<<2048, 256, 0, stream>>>(part, OT + (size_t)b * NC);
    }

    // out[b][c][n] = wp . o + bp + x
    gemm_nt2<64><<<dim3(4, 64, 2), 256, 0, stream>>>(
        wB + 786432, 0, 512, OT, NC, 512, d_out, CN, 4096, 512, bp, 1, x, CN, 1);
}

// Round 4
// 244.688 us; speedup vs baseline: 1.5613x; 1.0590x over previous
//
#include <hip/hip_runtime.h>
#include <stdint.h>

typedef short short8 __attribute__((ext_vector_type(8)));
typedef short short4v __attribute__((ext_vector_type(4)));
typedef float f32x4 __attribute__((ext_vector_type(4)));
typedef float float4v __attribute__((ext_vector_type(4)));

__device__ inline float bf2f(short s) {
    union { unsigned u; float f; } c;
    c.u = ((unsigned)(unsigned short)s) << 16;
    return c.f;
}
__device__ inline short f2bf(float f) {
    union { float f; unsigned u; } c;
    c.f = f;
    unsigned u = c.u;
    unsigned r = (u + 0x7fffu + ((u >> 16) & 1u)) >> 16;
    return (short)r;
}

typedef const __attribute__((address_space(1))) char GChar;
typedef __attribute__((address_space(3))) char LChar;
__device__ __forceinline__ void gload_lds16(const void* g, void* l) {
    __builtin_amdgcn_global_load_lds((GChar*)g, (LChar*)l, 16, 0, 0);
}

template<int N> __device__ __forceinline__ void wait_vm() {
    static_assert(N == 0 || N == 6 || N == 8, "unsupported vmcnt");
    if constexpr (N == 8)      asm volatile("s_waitcnt vmcnt(8)" ::: "memory");
    else if constexpr (N == 6) asm volatile("s_waitcnt vmcnt(6)" ::: "memory");
    else                       asm volatile("s_waitcnt vmcnt(0)" ::: "memory");
}

// ---------------- weight fp32 -> bf16 convert (with scale fold) ----------------
__global__ __launch_bounds__(256) void conv_w(const float* __restrict__ src, short* __restrict__ dst, float scale) {
    int i = (blockIdx.x * 256 + threadIdx.x) * 4;
    float4v v = *reinterpret_cast<const float4v*>(src + i);
    short4v o;
    o[0] = f2bf(v[0] * scale); o[1] = f2bf(v[1] * scale);
    o[2] = f2bf(v[2] * scale); o[3] = f2bf(v[3] * scale);
    *reinterpret_cast<short4v*>(dst + i) = o;
}

// bqk[0:512] = bq*s ; bqk[512:1024] = bk
__global__ __launch_bounds__(256) void prep_bias(const float* __restrict__ bq, const float* __restrict__ bk,
                                                 float* __restrict__ bqk, float s) {
    int i = blockIdx.x * 256 + threadIdx.x;
    bqk[i] = (i < 512) ? bq[i] * s : bk[i - 512];
}

// ---------------- GroupNorm stats: one block per (b,g) ----------------
__global__ __launch_bounds__(256) void gn_stats(const float* __restrict__ x, float* __restrict__ stats) {
    int bg = blockIdx.x;
    const float* p = x + (size_t)bg * (16 * 4096);
    float s = 0.f, ss = 0.f;
    for (int i = threadIdx.x * 4; i < 65536; i += 1024) {
        float4v q = *reinterpret_cast<const float4v*>(p + i);
        s  += q[0] + q[1] + q[2] + q[3];
        ss += q[0]*q[0] + q[1]*q[1] + q[2]*q[2] + q[3]*q[3];
    }
    #pragma unroll
    for (int off = 32; off >= 1; off >>= 1) {
        s  += __shfl_xor(s, off);
        ss += __shfl_xor(ss, off);
    }
    __shared__ float rs[8];
    int w = threadIdx.x >> 6, lane = threadIdx.x & 63;
    if (lane == 0) { rs[w] = s; rs[4 + w] = ss; }
    __syncthreads();
    if (threadIdx.x == 0) {
        float S1 = rs[0] + rs[1] + rs[2] + rs[3];
        float S2 = rs[4] + rs[5] + rs[6] + rs[7];
        float mean = S1 * (1.f / 65536.f);
        float var  = S2 * (1.f / 65536.f) - mean * mean;
        stats[bg * 2]     = mean;
        stats[bg * 2 + 1] = rsqrtf(var + 1e-6f);
    }
}

// ---------------- GN apply + transpose: x[b][c][n] -> hT[b][n][c] (bf16) ----------------
__global__ __launch_bounds__(256) void gn_apply_t(const float* __restrict__ x, const float* __restrict__ stats,
                                                  const float* __restrict__ scale, const float* __restrict__ bias,
                                                  short* __restrict__ hT) {
    __shared__ float t[64][65];
    int n0 = blockIdx.x * 64, c0 = blockIdx.y * 64, b = blockIdx.z;
    const float* xb = x + (size_t)b * 512 * 4096;
    int col = threadIdx.x & 63, rb = threadIdx.x >> 6;
    #pragma unroll
    for (int r = 0; r < 16; ++r) {
        int cl = rb + r * 4;
        int c = c0 + cl;
        int g = c >> 4;
        float mean = stats[(b * 32 + g) * 2];
        float rstd = stats[(b * 32 + g) * 2 + 1];
        float v = xb[(size_t)c * 4096 + n0 + col];
        t[col][cl] = (v - mean) * rstd * scale[c] + bias[c];
    }
    __syncthreads();
    short* hb = hT + (size_t)b * 4096 * 512;
    #pragma unroll
    for (int r = 0; r < 16; ++r) {
        int nl = rb + r * 4;
        hb[(size_t)(n0 + nl) * 512 + c0 + col] = f2bf(t[nl][col]);
    }
}

// ================ big-tile NT GEMM, counted-vmcnt 2-phase pipeline ================
// C[M][N] = A[M][K] * B[N][K]^T ; bf16 in, fp32 acc. 512 threads, 8 waves (WM x WN).
// Double-buffered LDS; prefetch stays in flight across raw s_barrier (vmcnt(LPT)).
// XOR-swizzled LDS via inverse-swizzled global source (linear LDS dest).
template<int BMT, int BNT, int WM, int WN>
__global__ __launch_bounds__(512) void gemm_nt3(
    const short* __restrict__ A, long sAb, int lda,
    const short* __restrict__ B, long sBb, int ldb,
    void* __restrict__ Cv, long sCb, int ldc,
    int K,
    const float* __restrict__ bias, int bias_mode,
    const float* __restrict__ res, long sResb,
    int c_fp32)
{
    constexpr int BUFB = (BMT + BNT) * 128;   // bytes per LDS buffer
    constexpr int ALPT = BMT / 64;            // A gloads per thread per stage
    constexpr int BLPT = BNT / 64;
    constexpr int LPT  = ALPT + BLPT;
    constexpr int MF   = BMT / WM / 16;       // m-frags per wave
    constexpr int NF   = BNT / WN / 16;       // n-frags per wave
    __shared__ __align__(16) char lds[2 * BUFB];

    const int tid = threadIdx.x;
    const int bm = blockIdx.x * BMT;
    const int bn = blockIdx.y * BNT;
    const int bz = blockIdx.z;

    const short* Ab = A + (size_t)bz * sAb;
    const short* Bb = B + (size_t)bz * sBb;

    const int w = tid >> 6;
    const int lane = tid & 63;
    const int wm = w / WN, wn = w % WN;
    const int wr = wm * (BMT / WM);
    const int wc = wn * (BNT / WN);

    f32x4 acc[MF][NF] = {};
    const int nk = K >> 6;

    auto stage = [&](int buf, int kt) {
        char* la = lds + buf * BUFB;
        char* lb = la + BMT * 128;
        #pragma unroll
        for (int i = 0; i < ALPT; ++i) {
            int ch = i * 512 + tid;
            int r = ch >> 3, c = ch & 7;
            gload_lds16(Ab + (size_t)(bm + r) * lda + kt + ((c ^ (r & 7)) << 3), la + ch * 16);
        }
        #pragma unroll
        for (int i = 0; i < BLPT; ++i) {
            int ch = i * 512 + tid;
            int r = ch >> 3, c = ch & 7;
            gload_lds16(Bb + (size_t)(bn + r) * ldb + kt + ((c ^ (r & 7)) << 3), lb + ch * 16);
        }
    };

    stage(0, 0);
    int cur = 0;
    for (int t = 0; t < nk; ++t) {
        if (t + 1 < nk) {
            stage(cur ^ 1, (t + 1) << 6);
            wait_vm<LPT>();          // tile t complete; tile t+1 stays in flight
        } else {
            wait_vm<0>();
        }
        __builtin_amdgcn_s_barrier();
        asm volatile("" ::: "memory");

        const char* la = lds + cur * BUFB;
        const char* lb = la + BMT * 128;
        #pragma unroll
        for (int ks = 0; ks < 2; ++ks) {
            const int kb = ks * 64 + (lane >> 4) * 16;
            short8 af[MF], bfv[NF];
            #pragma unroll
            for (int m = 0; m < MF; ++m) {
                int r = wr + m * 16 + (lane & 15);
                af[m] = *reinterpret_cast<const short8*>(la + r * 128 + (kb ^ ((r & 7) << 4)));
            }
            #pragma unroll
            for (int n = 0; n < NF; ++n) {
                int r = wc + n * 16 + (lane & 15);
                bfv[n] = *reinterpret_cast<const short8*>(lb + r * 128 + (kb ^ ((r & 7) << 4)));
            }
            #pragma unroll
            for (int m = 0; m < MF; ++m)
                #pragma unroll
                for (int n = 0; n < NF; ++n)
                    acc[m][n] = __builtin_amdgcn_mfma_f32_16x16x32_bf16(af[m], bfv[n], acc[m][n], 0, 0, 0);
        }
        asm volatile("" ::: "memory");
        __builtin_amdgcn_s_barrier();
        cur ^= 1;
    }

    const int row0 = (lane >> 4) * 4;
    const int col0 = lane & 15;
    short* Cb16 = (short*)Cv + (size_t)bz * sCb;
    float* Cf32 = (float*)Cv + (size_t)bz * sCb;
    const float* resb = res ? res + (size_t)bz * sResb : nullptr;

    #pragma unroll
    for (int m = 0; m < MF; ++m) {
        #pragma unroll
        for (int r = 0; r < 4; ++r) {
            int row = bm + wr + m * 16 + row0 + r;
            float bvr = (bias_mode == 1) ? bias[row] : 0.0f;
            #pragma unroll
            for (int n = 0; n < NF; ++n) {
                int col = bn + wc + n * 16 + col0;
                float v = acc[m][n][r];
                if (bias_mode == 1) v += bvr;
                else if (bias_mode == 2) v += bias[col];
                size_t idx = (size_t)row * ldc + col;
                if (c_fp32) {
                    if (resb) v += resb[idx];
                    Cf32[idx] = v;
                } else {
                    Cb16[idx] = f2bf(v);
                }
            }
        }
    }
}

// ---------------- small NT GEMM (4 waves, 128 x BNT) for skinny projections ----------------
template<int BNT>
__global__ __launch_bounds__(256) void gemm_nt2(
    const short* __restrict__ A, long sAb, int lda,
    const short* __restrict__ B, long sBb, int ldb,
    void* __restrict__ Cv, long sCb, int ldc,
    int K,
    const float* __restrict__ bias, int bias_mode,
    const float* __restrict__ res, long sResb,
    int c_fp32)
{
    constexpr int BMT = 128;
    constexpr int NF  = BNT / 32;
    constexpr int BUF = (BMT + BNT) * 128;
    __shared__ __align__(16) char lds[2 * BUF];

    const int tid = threadIdx.x;
    const int bm = blockIdx.x * BMT;
    const int bn = blockIdx.y * BNT;
    const int bz = blockIdx.z;

    const short* Ab = A + (size_t)bz * sAb;
    const short* Bb = B + (size_t)bz * sBb;

    const int w = tid >> 6;
    const int lane = tid & 63;
    const int wr = (w >> 1) * 64;
    const int wc = (w & 1) * (BNT / 2);

    f32x4 acc[4][NF] = {};
    const int nk = K >> 6;

    auto stage = [&](int buf, int kt) {
        char* la = lds + buf * BUF;
        char* lb = la + BMT * 128;
        #pragma unroll
        for (int i = 0; i < (BMT * 8) / 256; ++i) {
            int ch = i * 256 + tid;
            int r = ch >> 3, c = ch & 7;
            gload_lds16(Ab + (size_t)(bm + r) * lda + kt + ((c ^ (r & 7)) << 3), la + ch * 16);
        }
        #pragma unroll
        for (int i = 0; i < (BNT * 8) / 256; ++i) {
            int ch = i * 256 + tid;
            int r = ch >> 3, c = ch & 7;
            gload_lds16(Bb + (size_t)(bn + r) * ldb + kt + ((c ^ (r & 7)) << 3), lb + ch * 16);
        }
    };

    stage(0, 0);
    __syncthreads();

    int cur = 0;
    for (int t = 0; t < nk; ++t) {
        if (t + 1 < nk) stage(cur ^ 1, (t + 1) << 6);
        const char* la = lds + cur * BUF;
        const char* lb = la + BMT * 128;
        #pragma unroll
        for (int ks = 0; ks < 2; ++ks) {
            const int kb = ks * 64 + (lane >> 4) * 16;
            short8 af[4], bfv[NF];
            #pragma unroll
            for (int m = 0; m < 4; ++m) {
                int r = wr + m * 16 + (lane & 15);
                af[m] = *reinterpret_cast<const short8*>(la + r * 128 + (kb ^ ((r & 7) << 4)));
            }
            #pragma unroll
            for (int n = 0; n < NF; ++n) {
                int r = wc + n * 16 + (lane & 15);
                bfv[n] = *reinterpret_cast<const short8*>(lb + r * 128 + (kb ^ ((r & 7) << 4)));
            }
            #pragma unroll
            for (int m = 0; m < 4; ++m)
                #pragma unroll
                for (int n = 0; n < NF; ++n)
                    acc[m][n] = __builtin_amdgcn_mfma_f32_16x16x32_bf16(af[m], bfv[n], acc[m][n], 0, 0, 0);
        }
        if (t + 1 < nk) __syncthreads();
        cur ^= 1;
    }

    const int row0 = (lane >> 4) * 4;
    const int col0 = lane & 15;
    short* Cb16 = (short*)Cv + (size_t)bz * sCb;
    float* Cf32 = (float*)Cv + (size_t)bz * sCb;
    const float* resb = res ? res + (size_t)bz * sResb : nullptr;

    #pragma unroll
    for (int m = 0; m < 4; ++m) {
        #pragma unroll
        for (int r = 0; r < 4; ++r) {
            int row = bm + wr + m * 16 + row0 + r;
            float bvr = (bias_mode == 1) ? bias[row] : 0.0f;
            #pragma unroll
            for (int n = 0; n < NF; ++n) {
                int col = bn + wc + n * 16 + col0;
                float v = acc[m][n][r];
                if (bias_mode == 1) v += bvr;
                else if (bias_mode == 2) v += bias[col];
                size_t idx = (size_t)row * ldc + col;
                if (c_fp32) {
                    if (resb) v += resb[idx];
                    Cf32[idx] = v;
                } else {
                    Cb16[idx] = f2bf(v);
                }
            }
        }
    }
}

// ---------------- row softmax in-place on bf16 [4096] rows ----------------
__global__ __launch_bounds__(256) void softmax_rows(short* __restrict__ S) {
    const int N = 4096;
    short* p = S + (size_t)blockIdx.x * N + threadIdx.x * 16;
    short8 r0 = *reinterpret_cast<short8*>(p);
    short8 r1 = *reinterpret_cast<short8*>(p + 8);
    float v[16];
    #pragma unroll
    for (int i = 0; i < 8; ++i) { v[i] = bf2f(r0[i]); v[8 + i] = bf2f(r1[i]); }
    float mx = v[0];
    #pragma unroll
    for (int i = 1; i < 16; ++i) mx = fmaxf(mx, v[i]);
    #pragma unroll
    for (int off = 32; off >= 1; off >>= 1) mx = fmaxf(mx, __shfl_xor(mx, off));
    __shared__ float red[8];
    int w = threadIdx.x >> 6, lane = threadIdx.x & 63;
    if (lane == 0) red[w] = mx;
    __syncthreads();
    mx = fmaxf(fmaxf(red[0], red[1]), fmaxf(red[2], red[3]));
    float s = 0.f;
    #pragma unroll
    for (int i = 0; i < 16; ++i) { v[i] = __expf(v[i] - mx); s += v[i]; }
    #pragma unroll
    for (int off = 32; off >= 1; off >>= 1) s += __shfl_xor(s, off);
    if (lane == 0) red[4 + w] = s;
    __syncthreads();
    s = (red[4] + red[5]) + (red[6] + red[7]);
    float inv = 1.0f / s;
    #pragma unroll
    for (int i = 0; i < 8; ++i) { r0[i] = f2bf(v[i] * inv); r1[i] = f2bf(v[8 + i] * inv); }
    *reinterpret_cast<short8*>(p) = r0;
    *reinterpret_cast<short8*>(p + 8) = r1;
}

// ---------------- split-K reduce: OT_bf16 = sum of 4 fp32 partials ----------------
__global__ __launch_bounds__(256) void reduce4(const float* __restrict__ p, short* __restrict__ o) {
    const long NN = 4096L * 512L;
    int i = (blockIdx.x * 256 + threadIdx.x) * 4;
    float4v a = *reinterpret_cast<const float4v*>(p + i);
    float4v b = *reinterpret_cast<const float4v*>(p + NN + i);
    float4v c = *reinterpret_cast<const float4v*>(p + 2 * NN + i);
    float4v d = *reinterpret_cast<const float4v*>(p + 3 * NN + i);
    short4v o4;
    o4[0] = f2bf(a[0] + b[0] + c[0] + d[0]);
    o4[1] = f2bf(a[1] + b[1] + c[1] + d[1]);
    o4[2] = f2bf(a[2] + b[2] + c[2] + d[2]);
    o4[3] = f2bf(a[3] + b[3] + c[3] + d[3]);
    *reinterpret_cast<short4v*>(o + i) = o4;
}

extern "C" void kernel_launch(void* const* d_in, const int* in_sizes, int n_in,
                              void* d_out, int out_size, void* d_ws, size_t ws_size,
                              hipStream_t stream) {
    (void)in_sizes; (void)n_in; (void)out_size; (void)ws_size;
    const float* x        = (const float*)d_in[0];
    const float* gn_scale = (const float*)d_in[1];
    const float* gn_bias  = (const float*)d_in[2];
    const float* wq = (const float*)d_in[3];
    const float* bq = (const float*)d_in[4];
    const float* wk = (const float*)d_in[5];
    const float* bk = (const float*)d_in[6];
    const float* wv = (const float*)d_in[7];
    const float* bv = (const float*)d_in[8];
    const float* wp = (const float*)d_in[9];
    const float* bp = (const float*)d_in[10];

    char* ws = (char*)d_ws;
    const size_t MB = 1024 * 1024;
    short* hT   = (short*)(ws + 0);        // [2][4096][512] bf16    (8MB)
    short* QKT  = (short*)(ws + 8  * MB);  // [2][4096][1024] bf16  (16MB)
    short* V    = (short*)(ws + 24 * MB);  // [2][512][4096] bf16    (8MB)
    short* OT   = (short*)(ws + 32 * MB);  // [2][4096][512] bf16    (8MB)
    short* S    = (short*)(ws + 40 * MB);  // [4096][4096] bf16     (32MB, per-batch reuse)
    short* wB   = (short*)(ws + 72 * MB);  // wq,wk,wv,wp bf16       (2MB)
    float* stats= (float*)(ws + 74 * MB);  // 128 f
    float* bqk  = (float*)(ws + 74 * MB + 4096);  // 1024 f
    float* part = (float*)(ws + 75 * MB);  // [4][4096][512] fp32   (32MB, per-batch reuse)

    const long NC   = 4096L * 512L;
    const long CN   = 512L * 4096L;
    const long QKNC = 4096L * 1024L;
    const float attn_scale = 0.044194173824159216f;  // 512^-0.5

    conv_w<<<256, 256, 0, stream>>>(wq, wB,          attn_scale);
    conv_w<<<256, 256, 0, stream>>>(wk, wB + 262144, 1.0f);
    conv_w<<<256, 256, 0, stream>>>(wv, wB + 524288, 1.0f);
    conv_w<<<256, 256, 0, stream>>>(wp, wB + 786432, 1.0f);
    prep_bias<<<4, 256, 0, stream>>>(bq, bk, bqk, attn_scale);

    gn_stats<<<64, 256, 0, stream>>>(x, stats);
    gn_apply_t<<<dim3(64, 8, 2), 256, 0, stream>>>(x, stats, gn_scale, gn_bias, hT);

    // QK projection (merged): QKT[b][n][0:512]=Q*s, [512:1024]=K
    gemm_nt3<128, 256, 2, 4><<<dim3(32, 4, 2), 512, 0, stream>>>(
        hT, NC, 512, wB, 0, 512, QKT, QKNC, 1024, 512, bqk, 2, nullptr, 0, 0);
    // V[b][c][n]
    gemm_nt2<64><<<dim3(4, 64, 2), 256, 0, stream>>>(
        wB + 524288, 0, 512, hT, NC, 512, V, CN, 4096, 512, bv, 1, nullptr, 0, 0);

    for (int b = 0; b < 2; ++b) {
        const short* Qb = QKT + (size_t)b * QKNC;
        // S[i][j] = sum_c Q[i][c] K[j][c]  (scale pre-folded)
        gemm_nt3<256, 256, 4, 2><<<dim3(16, 16, 1), 512, 0, stream>>>(
            Qb, 0, 1024, Qb + 512, 0, 1024, S, 0, 4096, 512, nullptr, 0, nullptr, 0, 0);
        softmax_rows<<<4096, 256, 0, stream>>>(S);
        // PV split-K=4: z offsets A,B by 1024 cols (exact tiling); K=1024 per z
        gemm_nt3<128, 256, 2, 4><<<dim3(32, 2, 4), 512, 0, stream>>>(
            S, 1024, 4096, V + (size_t)b * CN, 1024, 4096, part, 4096L * 512L, 512, 1024,
            nullptr, 0, nullptr, 0, 1);
        reduce4<<<2048, 256, 0, stream>>>(part, OT + (size_t)b * NC);
    }

    // out[b][c][n] = wp . o + bp + x
    gemm_nt2<64><<<dim3(4, 64, 2), 256, 0, stream>>>(
        wB + 786432, 0, 512, OT, NC, 512, d_out, CN, 4096, 512, bp, 1, x, CN, 1);
}

// Round 5
// 230.218 us; speedup vs baseline: 1.6594x; 1.0629x over previous
//
#include <hip/hip_runtime.h>
#include <stdint.h>

typedef short short8 __attribute__((ext_vector_type(8)));
typedef short short4v __attribute__((ext_vector_type(4)));
typedef float f32x4 __attribute__((ext_vector_type(4)));
typedef float float4v __attribute__((ext_vector_type(4)));

__device__ inline float bf2f(short s) {
    union { unsigned u; float f; } c;
    c.u = ((unsigned)(unsigned short)s) << 16;
    return c.f;
}
__device__ inline short f2bf(float f) {
    union { float f; unsigned u; } c;
    c.f = f;
    unsigned u = c.u;
    unsigned r = (u + 0x7fffu + ((u >> 16) & 1u)) >> 16;
    return (short)r;
}

typedef const __attribute__((address_space(1))) char GChar;
typedef __attribute__((address_space(3))) char LChar;
__device__ __forceinline__ void gload_lds16(const void* g, void* l) {
    __builtin_amdgcn_global_load_lds((GChar*)g, (LChar*)l, 16, 0, 0);
}

template<int N> __device__ __forceinline__ void wait_vm() {
    static_assert(N == 0 || N == 4 || N == 6 || N == 8 || N == 12, "unsupported vmcnt");
    if constexpr (N == 12)     asm volatile("s_waitcnt vmcnt(12)" ::: "memory");
    else if constexpr (N == 8) asm volatile("s_waitcnt vmcnt(8)" ::: "memory");
    else if constexpr (N == 6) asm volatile("s_waitcnt vmcnt(6)" ::: "memory");
    else if constexpr (N == 4) asm volatile("s_waitcnt vmcnt(4)" ::: "memory");
    else                       asm volatile("s_waitcnt vmcnt(0)" ::: "memory");
}

// XCD-aware (x,y)-plane swizzle; requires gridDim.x*gridDim.y % 8 == 0.
__device__ __forceinline__ void swz_xy(int& bx, int& by) {
    int gx = gridDim.x;
    int nwg = gx * gridDim.y;
    int wg = by * gx + bx;
    int chunk = nwg >> 3;
    int swz = (wg & 7) * chunk + (wg >> 3);
    bx = swz % gx;
    by = swz / gx;
}

// ---------------- all-4 weight fp32 -> bf16 convert (wq scaled) ----------------
__global__ __launch_bounds__(256) void conv_w4(const float* __restrict__ w0, const float* __restrict__ w1,
                                               const float* __restrict__ w2, const float* __restrict__ w3,
                                               short* __restrict__ dst, float s0) {
    int idx = (blockIdx.x * 256 + threadIdx.x) * 4;
    int wi = idx >> 18;           // 262144 elements per weight
    int off = idx & 262143;
    const float* src = (wi == 0) ? w0 : (wi == 1) ? w1 : (wi == 2) ? w2 : w3;
    float sc = (wi == 0) ? s0 : 1.0f;
    float4v v = *reinterpret_cast<const float4v*>(src + off);
    short4v o;
    o[0] = f2bf(v[0] * sc); o[1] = f2bf(v[1] * sc);
    o[2] = f2bf(v[2] * sc); o[3] = f2bf(v[3] * sc);
    *reinterpret_cast<short4v*>(dst + idx) = o;
}

// bqk[0:512] = bq*s ; bqk[512:1024] = bk
__global__ __launch_bounds__(256) void prep_bias(const float* __restrict__ bq, const float* __restrict__ bk,
                                                 float* __restrict__ bqk, float s) {
    int i = blockIdx.x * 256 + threadIdx.x;
    bqk[i] = (i < 512) ? bq[i] * s : bk[i - 512];
}

// ---------------- GroupNorm stats: one block per (b,g) ----------------
__global__ __launch_bounds__(256) void gn_stats(const float* __restrict__ x, float* __restrict__ stats) {
    int bg = blockIdx.x;
    const float* p = x + (size_t)bg * (16 * 4096);
    float s = 0.f, ss = 0.f;
    for (int i = threadIdx.x * 4; i < 65536; i += 1024) {
        float4v q = *reinterpret_cast<const float4v*>(p + i);
        s  += q[0] + q[1] + q[2] + q[3];
        ss += q[0]*q[0] + q[1]*q[1] + q[2]*q[2] + q[3]*q[3];
    }
    #pragma unroll
    for (int off = 32; off >= 1; off >>= 1) {
        s  += __shfl_xor(s, off);
        ss += __shfl_xor(ss, off);
    }
    __shared__ float rs[8];
    int w = threadIdx.x >> 6, lane = threadIdx.x & 63;
    if (lane == 0) { rs[w] = s; rs[4 + w] = ss; }
    __syncthreads();
    if (threadIdx.x == 0) {
        float S1 = rs[0] + rs[1] + rs[2] + rs[3];
        float S2 = rs[4] + rs[5] + rs[6] + rs[7];
        float mean = S1 * (1.f / 65536.f);
        float var  = S2 * (1.f / 65536.f) - mean * mean;
        stats[bg * 2]     = mean;
        stats[bg * 2 + 1] = rsqrtf(var + 1e-6f);
    }
}

// ---------------- GN apply + transpose: x[b][c][n] -> hT[b][n][c] (bf16) ----------------
__global__ __launch_bounds__(256) void gn_apply_t(const float* __restrict__ x, const float* __restrict__ stats,
                                                  const float* __restrict__ scale, const float* __restrict__ bias,
                                                  short* __restrict__ hT) {
    __shared__ float t[64][65];
    int n0 = blockIdx.x * 64, c0 = blockIdx.y * 64, b = blockIdx.z;
    const float* xb = x + (size_t)b * 512 * 4096;
    int col = threadIdx.x & 63, rb = threadIdx.x >> 6;
    #pragma unroll
    for (int r = 0; r < 16; ++r) {
        int cl = rb + r * 4;
        int c = c0 + cl;
        int g = c >> 4;
        float mean = stats[(b * 32 + g) * 2];
        float rstd = stats[(b * 32 + g) * 2 + 1];
        float v = xb[(size_t)c * 4096 + n0 + col];
        t[col][cl] = (v - mean) * rstd * scale[c] + bias[c];
    }
    __syncthreads();
    short* hb = hT + (size_t)b * 4096 * 512;
    #pragma unroll
    for (int r = 0; r < 16; ++r) {
        int nl = rb + r * 4;
        hb[(size_t)(n0 + nl) * 512 + c0 + col] = f2bf(t[nl][col]);
    }
}

// ================ big-tile NT GEMM, counted-vmcnt 2-phase pipeline ================
// C[M][N] = A[M][K] * B[N][K]^T ; bf16 in, fp32 acc. 512 threads, 8 waves (WM x WN).
// z decomposition: zb = bz/zdiv, zs = bz%zdiv; base += zb*s?b1 + zs*s?b2.
template<int BMT, int BNT, int WM, int WN>
__global__ __launch_bounds__(512) void gemm_nt3(
    const short* __restrict__ A, int zdiv, long sAb1, long sAb2, int lda,
    const short* __restrict__ B, long sBb1, long sBb2, int ldb,
    void* __restrict__ Cv, long sCb1, long sCb2, int ldc,
    int K,
    const float* __restrict__ bias, int bias_mode,
    const float* __restrict__ res, long sResb,
    int c_fp32)
{
    constexpr int BUFB = (BMT + BNT) * 128;
    constexpr int ALPT = BMT / 64;
    constexpr int BLPT = BNT / 64;
    constexpr int LPT  = ALPT + BLPT;
    constexpr int MF   = BMT / WM / 16;
    constexpr int NF   = BNT / WN / 16;
    __shared__ __align__(16) char lds[2 * BUFB];

    const int tid = threadIdx.x;
    int bx = blockIdx.x, by = blockIdx.y;
    swz_xy(bx, by);
    const int bm = bx * BMT;
    const int bn = by * BNT;
    const int bz = blockIdx.z;
    const int zb = bz / zdiv, zs = bz % zdiv;

    const short* Ab = A + (size_t)zb * sAb1 + (size_t)zs * sAb2;
    const short* Bb = B + (size_t)zb * sBb1 + (size_t)zs * sBb2;

    const int w = tid >> 6;
    const int lane = tid & 63;
    const int wm = w / WN, wn = w % WN;
    const int wr = wm * (BMT / WM);
    const int wc = wn * (BNT / WN);

    f32x4 acc[MF][NF] = {};
    const int nk = K >> 6;

    auto stage = [&](int buf, int kt) {
        char* la = lds + buf * BUFB;
        char* lb = la + BMT * 128;
        #pragma unroll
        for (int i = 0; i < ALPT; ++i) {
            int ch = i * 512 + tid;
            int r = ch >> 3, c = ch & 7;
            gload_lds16(Ab + (size_t)(bm + r) * lda + kt + ((c ^ (r & 7)) << 3), la + ch * 16);
        }
        #pragma unroll
        for (int i = 0; i < BLPT; ++i) {
            int ch = i * 512 + tid;
            int r = ch >> 3, c = ch & 7;
            gload_lds16(Bb + (size_t)(bn + r) * ldb + kt + ((c ^ (r & 7)) << 3), lb + ch * 16);
        }
    };

    stage(0, 0);
    int cur = 0;
    for (int t = 0; t < nk; ++t) {
        if (t + 1 < nk) {
            stage(cur ^ 1, (t + 1) << 6);
            wait_vm<LPT>();          // tile t complete; tile t+1 stays in flight
        } else {
            wait_vm<0>();
        }
        __builtin_amdgcn_s_barrier();
        asm volatile("" ::: "memory");

        const char* la = lds + cur * BUFB;
        const char* lb = la + BMT * 128;
        #pragma unroll
        for (int ks = 0; ks < 2; ++ks) {
            const int kb = ks * 64 + (lane >> 4) * 16;
            short8 af[MF], bfv[NF];
            #pragma unroll
            for (int m = 0; m < MF; ++m) {
                int r = wr + m * 16 + (lane & 15);
                af[m] = *reinterpret_cast<const short8*>(la + r * 128 + (kb ^ ((r & 7) << 4)));
            }
            #pragma unroll
            for (int n = 0; n < NF; ++n) {
                int r = wc + n * 16 + (lane & 15);
                bfv[n] = *reinterpret_cast<const short8*>(lb + r * 128 + (kb ^ ((r & 7) << 4)));
            }
            #pragma unroll
            for (int m = 0; m < MF; ++m)
                #pragma unroll
                for (int n = 0; n < NF; ++n)
                    acc[m][n] = __builtin_amdgcn_mfma_f32_16x16x32_bf16(af[m], bfv[n], acc[m][n], 0, 0, 0);
        }
        asm volatile("" ::: "memory");
        __builtin_amdgcn_s_barrier();
        cur ^= 1;
    }

    const int row0 = (lane >> 4) * 4;
    const int col0 = lane & 15;
    short* Cb16 = (short*)Cv + (size_t)zb * sCb1 + (size_t)zs * sCb2;
    float* Cf32 = (float*)Cv + (size_t)zb * sCb1 + (size_t)zs * sCb2;
    const float* resb = res ? res + (size_t)zb * sResb : nullptr;

    #pragma unroll
    for (int m = 0; m < MF; ++m) {
        #pragma unroll
        for (int r = 0; r < 4; ++r) {
            int row = bm + wr + m * 16 + row0 + r;
            float bvr = (bias_mode == 1) ? bias[row] : 0.0f;
            #pragma unroll
            for (int n = 0; n < NF; ++n) {
                int col = bn + wc + n * 16 + col0;
                float v = acc[m][n][r];
                if (bias_mode == 1) v += bvr;
                else if (bias_mode == 2) v += bias[col];
                size_t idx = (size_t)row * ldc + col;
                if (c_fp32) {
                    if (resb) v += resb[idx];
                    Cf32[idx] = v;
                } else {
                    Cb16[idx] = f2bf(v);
                }
            }
        }
    }
}

// ---------------- small NT GEMM (4 waves, 128 x BNT), counted-vmcnt pipeline ----------------
template<int BNT>
__global__ __launch_bounds__(256) void gemm_nt2(
    const short* __restrict__ A, long sAb, int lda,
    const short* __restrict__ B, long sBb, int ldb,
    void* __restrict__ Cv, long sCb, int ldc,
    int K,
    const float* __restrict__ bias, int bias_mode,
    const float* __restrict__ res, long sResb,
    int c_fp32)
{
    constexpr int BMT = 128;
    constexpr int NF  = BNT / 32;
    constexpr int BUF = (BMT + BNT) * 128;
    constexpr int ALPT = (BMT * 8) / 256;
    constexpr int BLPT = (BNT * 8) / 256;
    constexpr int LPT  = ALPT + BLPT;
    __shared__ __align__(16) char lds[2 * BUF];

    const int tid = threadIdx.x;
    int bx = blockIdx.x, by = blockIdx.y;
    swz_xy(bx, by);
    const int bm = bx * BMT;
    const int bn = by * BNT;
    const int bz = blockIdx.z;

    const short* Ab = A + (size_t)bz * sAb;
    const short* Bb = B + (size_t)bz * sBb;

    const int w = tid >> 6;
    const int lane = tid & 63;
    const int wr = (w >> 1) * 64;
    const int wc = (w & 1) * (BNT / 2);

    f32x4 acc[4][NF] = {};
    const int nk = K >> 6;

    auto stage = [&](int buf, int kt) {
        char* la = lds + buf * BUF;
        char* lb = la + BMT * 128;
        #pragma unroll
        for (int i = 0; i < ALPT; ++i) {
            int ch = i * 256 + tid;
            int r = ch >> 3, c = ch & 7;
            gload_lds16(Ab + (size_t)(bm + r) * lda + kt + ((c ^ (r & 7)) << 3), la + ch * 16);
        }
        #pragma unroll
        for (int i = 0; i < BLPT; ++i) {
            int ch = i * 256 + tid;
            int r = ch >> 3, c = ch & 7;
            gload_lds16(Bb + (size_t)(bn + r) * ldb + kt + ((c ^ (r & 7)) << 3), lb + ch * 16);
        }
    };

    stage(0, 0);
    int cur = 0;
    for (int t = 0; t < nk; ++t) {
        if (t + 1 < nk) {
            stage(cur ^ 1, (t + 1) << 6);
            wait_vm<LPT>();
        } else {
            wait_vm<0>();
        }
        __builtin_amdgcn_s_barrier();
        asm volatile("" ::: "memory");

        const char* la = lds + cur * BUF;
        const char* lb = la + BMT * 128;
        #pragma unroll
        for (int ks = 0; ks < 2; ++ks) {
            const int kb = ks * 64 + (lane >> 4) * 16;
            short8 af[4], bfv[NF];
            #pragma unroll
            for (int m = 0; m < 4; ++m) {
                int r = wr + m * 16 + (lane & 15);
                af[m] = *reinterpret_cast<const short8*>(la + r * 128 + (kb ^ ((r & 7) << 4)));
            }
            #pragma unroll
            for (int n = 0; n < NF; ++n) {
                int r = wc + n * 16 + (lane & 15);
                bfv[n] = *reinterpret_cast<const short8*>(lb + r * 128 + (kb ^ ((r & 7) << 4)));
            }
            #pragma unroll
            for (int m = 0; m < 4; ++m)
                #pragma unroll
                for (int n = 0; n < NF; ++n)
                    acc[m][n] = __builtin_amdgcn_mfma_f32_16x16x32_bf16(af[m], bfv[n], acc[m][n], 0, 0, 0);
        }
        asm volatile("" ::: "memory");
        __builtin_amdgcn_s_barrier();
        cur ^= 1;
    }

    const int row0 = (lane >> 4) * 4;
    const int col0 = lane & 15;
    short* Cb16 = (short*)Cv + (size_t)bz * sCb;
    float* Cf32 = (float*)Cv + (size_t)bz * sCb;
    const float* resb = res ? res + (size_t)bz * sResb : nullptr;

    #pragma unroll
    for (int m = 0; m < 4; ++m) {
        #pragma unroll
        for (int r = 0; r < 4; ++r) {
            int row = bm + wr + m * 16 + row0 + r;
            float bvr = (bias_mode == 1) ? bias[row] : 0.0f;
            #pragma unroll
            for (int n = 0; n < NF; ++n) {
                int col = bn + wc + n * 16 + col0;
                float v = acc[m][n][r];
                if (bias_mode == 1) v += bvr;
                else if (bias_mode == 2) v += bias[col];
                size_t idx = (size_t)row * ldc + col;
                if (c_fp32) {
                    if (resb) v += resb[idx];
                    Cf32[idx] = v;
                } else {
                    Cb16[idx] = f2bf(v);
                }
            }
        }
    }
}

// ---------------- row softmax in-place on bf16 [4096] rows (both batches) ----------------
__global__ __launch_bounds__(256) void softmax_rows(short* __restrict__ S) {
    const int N = 4096;
    short* p = S + (size_t)blockIdx.x * N + threadIdx.x * 16;
    short8 r0 = *reinterpret_cast<short8*>(p);
    short8 r1 = *reinterpret_cast<short8*>(p + 8);
    float v[16];
    #pragma unroll
    for (int i = 0; i < 8; ++i) { v[i] = bf2f(r0[i]); v[8 + i] = bf2f(r1[i]); }
    float mx = v[0];
    #pragma unroll
    for (int i = 1; i < 16; ++i) mx = fmaxf(mx, v[i]);
    #pragma unroll
    for (int off = 32; off >= 1; off >>= 1) mx = fmaxf(mx, __shfl_xor(mx, off));
    __shared__ float red[8];
    int w = threadIdx.x >> 6, lane = threadIdx.x & 63;
    if (lane == 0) red[w] = mx;
    __syncthreads();
    mx = fmaxf(fmaxf(red[0], red[1]), fmaxf(red[2], red[3]));
    float s = 0.f;
    #pragma unroll
    for (int i = 0; i < 16; ++i) { v[i] = __expf(v[i] - mx); s += v[i]; }
    #pragma unroll
    for (int off = 32; off >= 1; off >>= 1) s += __shfl_xor(s, off);
    if (lane == 0) red[4 + w] = s;
    __syncthreads();
    s = (red[4] + red[5]) + (red[6] + red[7]);
    float inv = 1.0f / s;
    #pragma unroll
    for (int i = 0; i < 8; ++i) { r0[i] = f2bf(v[i] * inv); r1[i] = f2bf(v[8 + i] * inv); }
    *reinterpret_cast<short8*>(p) = r0;
    *reinterpret_cast<short8*>(p + 8) = r1;
}

// ---------------- split-K reduce: OT_bf16 = sum of 4 fp32 partials (grid.y = batch) ----------------
__global__ __launch_bounds__(256) void reduce4(const float* __restrict__ p, short* __restrict__ o) {
    const long NN = 4096L * 512L;
    const float* pb = p + (size_t)blockIdx.y * 4 * NN;
    short* ob = o + (size_t)blockIdx.y * NN;
    int i = (blockIdx.x * 256 + threadIdx.x) * 4;
    float4v a = *reinterpret_cast<const float4v*>(pb + i);
    float4v b = *reinterpret_cast<const float4v*>(pb + NN + i);
    float4v c = *reinterpret_cast<const float4v*>(pb + 2 * NN + i);
    float4v d = *reinterpret_cast<const float4v*>(pb + 3 * NN + i);
    short4v o4;
    o4[0] = f2bf(a[0] + b[0] + c[0] + d[0]);
    o4[1] = f2bf(a[1] + b[1] + c[1] + d[1]);
    o4[2] = f2bf(a[2] + b[2] + c[2] + d[2]);
    o4[3] = f2bf(a[3] + b[3] + c[3] + d[3]);
    *reinterpret_cast<short4v*>(ob + i) = o4;
}

extern "C" void kernel_launch(void* const* d_in, const int* in_sizes, int n_in,
                              void* d_out, int out_size, void* d_ws, size_t ws_size,
                              hipStream_t stream) {
    (void)in_sizes; (void)n_in; (void)out_size; (void)ws_size;
    const float* x        = (const float*)d_in[0];
    const float* gn_scale = (const float*)d_in[1];
    const float* gn_bias  = (const float*)d_in[2];
    const float* wq = (const float*)d_in[3];
    const float* bq = (const float*)d_in[4];
    const float* wk = (const float*)d_in[5];
    const float* bk = (const float*)d_in[6];
    const float* wv = (const float*)d_in[7];
    const float* bv = (const float*)d_in[8];
    const float* wp = (const float*)d_in[9];
    const float* bp = (const float*)d_in[10];

    char* ws = (char*)d_ws;
    const size_t MB = 1024 * 1024;
    short* hT   = (short*)(ws + 0);         // [2][4096][512] bf16     (8MB)
    short* QKT  = (short*)(ws + 8   * MB);  // [2][4096][1024] bf16   (16MB)
    short* V    = (short*)(ws + 24  * MB);  // [2][512][4096] bf16     (8MB)
    short* OT   = (short*)(ws + 32  * MB);  // [2][4096][512] bf16     (8MB)
    short* S    = (short*)(ws + 40  * MB);  // [2][4096][4096] bf16   (64MB)
    float* part = (float*)(ws + 104 * MB);  // [2][4][4096][512] fp32 (64MB)
    short* wB   = (short*)(ws + 168 * MB);  // wq,wk,wv,wp bf16        (2MB)
    float* stats= (float*)(ws + 170 * MB);  // 128 f
    float* bqk  = (float*)(ws + 170 * MB + 4096);  // 1024 f

    const long NC   = 4096L * 512L;    // 2M
    const long CN   = 512L * 4096L;
    const long QKNC = 4096L * 1024L;   // 4M
    const long SNN  = 4096L * 4096L;   // 16M
    const float attn_scale = 0.044194173824159216f;  // 512^-0.5

    conv_w4<<<1024, 256, 0, stream>>>(wq, wk, wv, wp, wB, attn_scale);
    prep_bias<<<4, 256, 0, stream>>>(bq, bk, bqk, attn_scale);

    gn_stats<<<64, 256, 0, stream>>>(x, stats);
    gn_apply_t<<<dim3(64, 8, 2), 256, 0, stream>>>(x, stats, gn_scale, gn_bias, hT);

    // QK projection (merged): QKT[b][n][0:512]=Q*s, [512:1024]=K
    gemm_nt3<128, 256, 2, 4><<<dim3(32, 4, 2), 512, 0, stream>>>(
        hT, 1, NC, 0, 512, wB, 0, 0, 512, QKT, QKNC, 0, 1024, 512, bqk, 2, nullptr, 0, 0);
    // V[b][c][n]
    gemm_nt2<64><<<dim3(4, 64, 2), 256, 0, stream>>>(
        wB + 524288, 0, 512, hT, NC, 512, V, CN, 4096, 512, bv, 1, nullptr, 0, 0);

    // S[b][i][j] = sum_c Q[i][c] K[j][c]  (scale pre-folded), both batches
    gemm_nt3<256, 256, 4, 2><<<dim3(16, 16, 2), 512, 0, stream>>>(
        QKT, 1, QKNC, 0, 1024, QKT + 512, QKNC, 0, 1024, S, SNN, 0, 4096, 512,
        nullptr, 0, nullptr, 0, 0);
    softmax_rows<<<8192, 256, 0, stream>>>(S);
    // PV split-K=4, both batches: z = batch*4 + slice
    gemm_nt3<128, 256, 2, 4><<<dim3(32, 2, 8), 512, 0, stream>>>(
        S, 4, SNN, 1024, 4096, V, CN, 1024, 4096, part, 4L * NC, NC, 512, 1024,
        nullptr, 0, nullptr, 0, 1);
    reduce4<<<dim3(2048, 2), 256, 0, stream>>>(part, OT);

    // out[b][c][n] = wp . o + bp + x
    gemm_nt2<64><<<dim3(4, 64, 2), 256, 0, stream>>>(
        wB + 786432, 0, 512, OT, NC, 512, d_out, CN, 4096, 512, bp, 1, x, CN, 1);
}